// Round 1
// baseline (123.759 us; speedup 1.0000x reference)
//
#include <hip/hip_runtime.h>

// Bilinear warp: out[b,c,h,w] = bilerp(img[b,c], (w+flo[b,0,h,w], h+flo[b,1,h,w]))
// img: [8,16,512,512] f32, flo: [8,2,512,512] f32, out: [8,16,512,512] f32.

#define BB 8
#define CC 16
#define HH 512
#define WW 512

__global__ __launch_bounds__(256) void warp_bilinear_kernel(
    const float* __restrict__ img,
    const float* __restrict__ flo,
    float* __restrict__ out)
{
    const int HW = HH * WW;
    int gid = blockIdx.x * blockDim.x + threadIdx.x;   // over B*H*W
    if (gid >= BB * HW) return;

    int b  = gid / HW;
    int hw = gid - b * HW;
    int h  = hw >> 9;          // /512
    int w  = hw & (WW - 1);    // %512

    // flow (coalesced: hw is innermost)
    float fx = flo[(b * 2 + 0) * HW + hw];
    float fy = flo[(b * 2 + 1) * HW + hw];

    float pos_x = (float)w + fx;
    float pos_y = (float)h + fy;

    float x0f = floorf(pos_x);
    float y0f = floorf(pos_y);
    float xw  = pos_x - x0f;   // weights from UNclamped floor (matches reference)
    float yw  = pos_y - y0f;

    // clamp-then-truncate; values >= 0 after clamp so trunc == floor
    int x0 = (int)fminf(fmaxf(x0f,        0.0f), (float)(WW - 1));
    int x1 = (int)fminf(fmaxf(x0f + 1.0f, 0.0f), (float)(WW - 1));
    int y0 = (int)fminf(fmaxf(y0f,        0.0f), (float)(HH - 1));
    int y1 = (int)fminf(fmaxf(y0f + 1.0f, 0.0f), (float)(HH - 1));

    float wa = (1.0f - xw) * (1.0f - yw);
    float wb = (1.0f - xw) * yw;
    float wc = xw * (1.0f - yw);
    float wd = xw * yw;

    int i00 = y0 * WW + x0;    // (y0,x0)
    int i10 = y1 * WW + x0;    // (y1,x0)
    int i01 = y0 * WW + x1;    // (y0,x1)
    int i11 = y1 * WW + x1;    // (y1,x1)

    const float* imgb = img + (size_t)b * CC * HW;
    float*       outb = out + (size_t)b * CC * HW;

    #pragma unroll
    for (int c = 0; c < CC; ++c) {
        const float* p = imgb + c * HW;
        float Ia = p[i00];
        float Ib = p[i10];
        float Ic = p[i01];
        float Id = p[i11];
        outb[c * HW + hw] = wa * Ia + wb * Ib + wc * Ic + wd * Id;
    }
}

extern "C" void kernel_launch(void* const* d_in, const int* in_sizes, int n_in,
                              void* d_out, int out_size, void* d_ws, size_t ws_size,
                              hipStream_t stream)
{
    const float* img = (const float*)d_in[0];
    const float* flo = (const float*)d_in[1];
    float*       out = (float*)d_out;

    const int total = BB * HH * WW;            // one thread per pixel, loops 16 channels
    const int block = 256;
    const int grid  = (total + block - 1) / block;

    warp_bilinear_kernel<<<grid, block, 0, stream>>>(img, flo, out);
}

// Round 2
// 103.720 us; speedup vs baseline: 1.1932x; 1.1932x over previous
//
#include <hip/hip_runtime.h>

// Bilinear warp: out[b,c,h,w] = bilerp(img[b,c], (w+flo[b,0,h,w], h+flo[b,1,h,w]))
// img: [8,16,512,512] f32, flo: [8,2,512,512] f32, out: [8,16,512,512] f32.
//
// Round 2: XCD-aware swizzle (XCD k <- batch k), 2D 64x4 block tiles for
// vertical L1/L2 locality, non-temporal stores/flo-loads to keep L2 for img.

#define BB 8
#define CC 16
#define HH 512
#define WW 512

#define TILE_W 64
#define TILE_H 4
#define TILES_X (WW / TILE_W)            // 8
#define TILES_Y (HH / TILE_H)            // 128
#define TILES_PER_IMG (TILES_X * TILES_Y) // 1024
#define NBLOCKS (BB * TILES_PER_IMG)      // 8192
#define NXCD 8

__global__ __launch_bounds__(256) void warp_bilinear_kernel(
    const float* __restrict__ img,
    const float* __restrict__ flo,
    float* __restrict__ out)
{
    const int HW = HH * WW;

    // XCD swizzle: dispatch round-robins blocks across 8 XCDs (bid % 8).
    // Remap so XCD k processes work-chunk [k*1024, (k+1)*1024) = batch k,
    // tiles in row-major (top-to-bottom) order. 8192 = 8*1024, bijective.
    int bid = blockIdx.x;
    int wk  = (bid % NXCD) * (NBLOCKS / NXCD) + bid / NXCD;

    int b    = wk / TILES_PER_IMG;
    int tile = wk - b * TILES_PER_IMG;
    int ty   = tile / TILES_X;
    int tx   = tile - ty * TILES_X;

    int w = tx * TILE_W + (threadIdx.x & (TILE_W - 1));
    int h = ty * TILE_H + (threadIdx.x >> 6);
    int hw = h * WW + w;

    // flow (coalesced within wave: consecutive w). Non-temporal: read once.
    float fx = __builtin_nontemporal_load(&flo[(b * 2 + 0) * HW + hw]);
    float fy = __builtin_nontemporal_load(&flo[(b * 2 + 1) * HW + hw]);

    float pos_x = (float)w + fx;
    float pos_y = (float)h + fy;

    float x0f = floorf(pos_x);
    float y0f = floorf(pos_y);
    float xw  = pos_x - x0f;   // weights from UNclamped floor (matches reference)
    float yw  = pos_y - y0f;

    // clamp-then-truncate; values >= 0 after clamp so trunc == floor
    int x0 = (int)fminf(fmaxf(x0f,        0.0f), (float)(WW - 1));
    int x1 = (int)fminf(fmaxf(x0f + 1.0f, 0.0f), (float)(WW - 1));
    int y0 = (int)fminf(fmaxf(y0f,        0.0f), (float)(HH - 1));
    int y1 = (int)fminf(fmaxf(y0f + 1.0f, 0.0f), (float)(HH - 1));

    float wa = (1.0f - xw) * (1.0f - yw);
    float wb = (1.0f - xw) * yw;
    float wc = xw * (1.0f - yw);
    float wd = xw * yw;

    int i00 = y0 * WW + x0;
    int i10 = y1 * WW + x0;
    int i01 = y0 * WW + x1;
    int i11 = y1 * WW + x1;

    const float* imgb = img + (size_t)b * CC * HW;
    float*       outb = out + (size_t)b * CC * HW;

    #pragma unroll
    for (int c = 0; c < CC; ++c) {
        const float* p = imgb + c * HW;
        float Ia = p[i00];
        float Ib = p[i10];
        float Ic = p[i01];
        float Id = p[i11];
        float v  = wa * Ia + wb * Ib + wc * Ic + wd * Id;
        // out is never re-read: bypass L2 so img lines stay resident
        __builtin_nontemporal_store(v, &outb[c * HW + hw]);
    }
}

extern "C" void kernel_launch(void* const* d_in, const int* in_sizes, int n_in,
                              void* d_out, int out_size, void* d_ws, size_t ws_size,
                              hipStream_t stream)
{
    const float* img = (const float*)d_in[0];
    const float* flo = (const float*)d_in[1];
    float*       out = (float*)d_out;

    warp_bilinear_kernel<<<NBLOCKS, 256, 0, stream>>>(img, flo, out);
}

// Round 3
// 71.088 us; speedup vs baseline: 1.7409x; 1.4590x over previous
//
#include <hip/hip_runtime.h>

// Bilinear warp: out[b,c,h,w] = bilerp(img[b,c], (w+flo[b,0,h,w], h+flo[b,1,h,w]))
// img: [8,16,512,512] f32, flo: [8,2,512,512] f32, out: [8,16,512,512] f32.
//
// Round 3: VMEM-instruction-bound (24 cy/VMEM measured). Cut instr count:
//  - merge (x0,x1) corner pair into ONE float2 gather (x1 is always x0 or x0+1);
//    boundary select folded into precomputed weights -> no per-channel cndmask
//  - 4 px/thread: float4 flo loads + float4 NT stores
//  - keep XCD-batch swizzle + non-temporal stores (R2 win: FETCH 284->74MB)

#define BB 8
#define CC 16
#define HH 512
#define WW 512
#define HWSZ (HH * WW)

#define TILE_W 256              // pixels per block in x (64 lanes * 4 px)
#define TILE_H 4                // rows per block
#define TILES_X (WW / TILE_W)   // 2
#define TILES_Y (HH / TILE_H)   // 128
#define TILES_PER_IMG (TILES_X * TILES_Y)  // 256
#define NBLOCKS (BB * TILES_PER_IMG)       // 2048 (= 8 * 256, swizzle bijective)
#define NXCD 8

typedef float f2u __attribute__((ext_vector_type(2), aligned(4)));  // 4B-aligned pair
typedef float f4  __attribute__((ext_vector_type(4)));

__global__ __launch_bounds__(256) void warp_bilinear_kernel(
    const float* __restrict__ img,
    const float* __restrict__ flo,
    float* __restrict__ out)
{
    // XCD swizzle: XCD k <- batch k, tiles top-to-bottom (2048 = 8*256).
    int bid = blockIdx.x;
    int wk  = (bid % NXCD) * (NBLOCKS / NXCD) + bid / NXCD;

    int b    = wk / TILES_PER_IMG;
    int tile = wk - b * TILES_PER_IMG;
    int ty   = tile / TILES_X;
    int tx   = tile - ty * TILES_X;

    int lane = threadIdx.x & 63;     // wave = one row of 256 px
    int row  = threadIdx.x >> 6;
    int h    = ty * TILE_H + row;
    int w0   = tx * TILE_W + lane * 4;
    int hw   = h * WW + w0;

    // flow: 16B-aligned float4 loads, non-temporal (read exactly once)
    f4 fx4 = __builtin_nontemporal_load((const f4*)(flo + (size_t)(b * 2 + 0) * HWSZ + hw));
    f4 fy4 = __builtin_nontemporal_load((const f4*)(flo + (size_t)(b * 2 + 1) * HWSZ + hw));

    // Per-pixel precompute: merged-pair base offsets + boundary-folded weights.
    // x1 in {x0, x0+1}; load float2 at xb=min(x0,W-2) so both corners are in it.
    //   value(x0) = (x0==xb) ? t.x : t.y   -> fold into weights:
    //   top contribution = wtx*t.x + wty*t.y   (wtx+wty = wa+wc)
    int   ib0[4], ib1[4];
    float wtx[4], wty[4], wbx[4], wby[4];
    #pragma unroll
    for (int i = 0; i < 4; ++i) {
        float pos_x = (float)(w0 + i) + fx4[i];
        float pos_y = (float)h + fy4[i];

        float x0f = floorf(pos_x);
        float y0f = floorf(pos_y);
        float xw  = pos_x - x0f;     // weights from UNclamped floor (reference)
        float yw  = pos_y - y0f;

        int x0 = (int)fminf(fmaxf(x0f,        0.0f), (float)(WW - 1));
        int x1 = (int)fminf(fmaxf(x0f + 1.0f, 0.0f), (float)(WW - 1));
        int y0 = (int)fminf(fmaxf(y0f,        0.0f), (float)(HH - 1));
        int y1 = (int)fminf(fmaxf(y0f + 1.0f, 0.0f), (float)(HH - 1));

        int xb = min(x0, WW - 2);    // float2 window [xb, xb+1], never OOB

        float wa = (1.0f - xw) * (1.0f - yw);
        float wb = (1.0f - xw) * yw;
        float wc = xw * (1.0f - yw);
        float wd = xw * yw;

        float tx_ = (x0 == xb ? wa : 0.0f) + (x1 == xb ? wc : 0.0f);
        float bx_ = (x0 == xb ? wb : 0.0f) + (x1 == xb ? wd : 0.0f);
        wtx[i] = tx_;  wty[i] = (wa + wc) - tx_;
        wbx[i] = bx_;  wby[i] = (wb + wd) - bx_;

        ib0[i] = y0 * WW + xb;
        ib1[i] = y1 * WW + xb;
    }

    const float* imgb = img + (size_t)b * CC * HWSZ;
    float*       outb = out + (size_t)b * CC * HWSZ;

    #pragma unroll
    for (int c = 0; c < CC; ++c) {
        const float* p = imgb + c * HWSZ;
        f4 v;
        #pragma unroll
        for (int i = 0; i < 4; ++i) {
            f2u t  = *(const f2u*)(p + ib0[i]);   // (y0, xb..xb+1)
            f2u bo = *(const f2u*)(p + ib1[i]);   // (y1, xb..xb+1)
            v[i] = wtx[i] * t.x + wty[i] * t.y + wbx[i] * bo.x + wby[i] * bo.y;
        }
        // out never re-read: bypass L2, keep it for img
        __builtin_nontemporal_store(v, (f4*)(outb + (size_t)c * HWSZ + hw));
    }
}

extern "C" void kernel_launch(void* const* d_in, const int* in_sizes, int n_in,
                              void* d_out, int out_size, void* d_ws, size_t ws_size,
                              hipStream_t stream)
{
    const float* img = (const float*)d_in[0];
    const float* flo = (const float*)d_in[1];
    float*       out = (float*)d_out;

    warp_bilinear_kernel<<<NBLOCKS, 256, 0, stream>>>(img, flo, out);
}

// Round 4
// 65.864 us; speedup vs baseline: 1.8790x; 1.0793x over previous
//
#include <hip/hip_runtime.h>

// Bilinear warp: out[b,c,h,w] = bilerp(img[b,c], (w+flo[b,0,h,w], h+flo[b,1,h,w]))
// img: [8,16,512,512] f32, flo: [8,2,512,512] f32, out: [8,16,512,512] f32.
//
// Round 4: R3 was latency-bound (VGPR=24 -> <8 loads in flight). Keep the
// merged-float2 gathers, 4px/thread, XCD-batch swizzle, NT stores; add an
// explicit 4-channel-deep software pipeline with NAMED register buffers so
// ~32 gathers stay outstanding per thread (compile-time indices only).

#define BB 8
#define CC 16
#define HH 512
#define WW 512
#define HWSZ (HH * WW)

#define TILE_W 256              // pixels per block in x (64 lanes * 4 px)
#define TILE_H 4                // rows per block
#define TILES_X (WW / TILE_W)   // 2
#define TILES_Y (HH / TILE_H)   // 128
#define TILES_PER_IMG (TILES_X * TILES_Y)  // 256
#define NBLOCKS (BB * TILES_PER_IMG)       // 2048 (= 8 * 256, swizzle bijective)
#define NXCD 8

typedef float f2u __attribute__((ext_vector_type(2), aligned(4)));  // 4B-aligned pair
typedef float f4  __attribute__((ext_vector_type(4)));

__global__ __launch_bounds__(256, 1) void warp_bilinear_kernel(
    const float* __restrict__ img,
    const float* __restrict__ flo,
    float* __restrict__ out)
{
    // XCD swizzle: XCD k <- batch k, tiles top-to-bottom (2048 = 8*256).
    int bid = blockIdx.x;
    int wk  = (bid % NXCD) * (NBLOCKS / NXCD) + bid / NXCD;

    int b    = wk / TILES_PER_IMG;
    int tile = wk - b * TILES_PER_IMG;
    int ty   = tile / TILES_X;
    int tx   = tile - ty * TILES_X;

    int lane = threadIdx.x & 63;     // wave = one row of 256 px
    int row  = threadIdx.x >> 6;
    int h    = ty * TILE_H + row;
    int w0   = tx * TILE_W + lane * 4;
    int hw   = h * WW + w0;

    // flow: 16B-aligned float4 loads, non-temporal (read exactly once)
    f4 fx4 = __builtin_nontemporal_load((const f4*)(flo + (size_t)(b * 2 + 0) * HWSZ + hw));
    f4 fy4 = __builtin_nontemporal_load((const f4*)(flo + (size_t)(b * 2 + 1) * HWSZ + hw));

    // Per-pixel precompute: merged-pair base offsets + boundary-folded weights.
    // x1 in {x0, x0+1}; load float2 at xb=min(x0,W-2) so both corners are in it.
    int   ib0[4], ib1[4];
    float wtx[4], wty[4], wbx[4], wby[4];
    #pragma unroll
    for (int i = 0; i < 4; ++i) {
        float pos_x = (float)(w0 + i) + fx4[i];
        float pos_y = (float)h + fy4[i];

        float x0f = floorf(pos_x);
        float y0f = floorf(pos_y);
        float xw  = pos_x - x0f;     // weights from UNclamped floor (reference)
        float yw  = pos_y - y0f;

        int x0 = (int)fminf(fmaxf(x0f,        0.0f), (float)(WW - 1));
        int x1 = (int)fminf(fmaxf(x0f + 1.0f, 0.0f), (float)(WW - 1));
        int y0 = (int)fminf(fmaxf(y0f,        0.0f), (float)(HH - 1));
        int y1 = (int)fminf(fmaxf(y0f + 1.0f, 0.0f), (float)(HH - 1));

        int xb = min(x0, WW - 2);    // float2 window [xb, xb+1], never OOB

        float wa = (1.0f - xw) * (1.0f - yw);
        float wb = (1.0f - xw) * yw;
        float wc = xw * (1.0f - yw);
        float wd = xw * yw;

        float tx_ = (x0 == xb ? wa : 0.0f) + (x1 == xb ? wc : 0.0f);
        float bx_ = (x0 == xb ? wb : 0.0f) + (x1 == xb ? wd : 0.0f);
        wtx[i] = tx_;  wty[i] = (wa + wc) - tx_;
        wbx[i] = bx_;  wby[i] = (wb + wd) - bx_;

        ib0[i] = y0 * WW + xb;
        ib1[i] = y1 * WW + xb;
    }

    const float* imgb = img + (size_t)b * CC * HWSZ;
    float*       outb = out + (size_t)b * CC * HWSZ;

    // 4-deep software pipeline over channels. Named buffers, compile-time
    // indices only (runtime-indexed arrays would spill to scratch).
    auto loadc = [&](f2u (&t)[4], f2u (&bo)[4], int c) {
        const float* p = imgb + (size_t)c * HWSZ;
        #pragma unroll
        for (int i = 0; i < 4; ++i) {
            t[i]  = *(const f2u*)(p + ib0[i]);   // (y0, xb..xb+1)
            bo[i] = *(const f2u*)(p + ib1[i]);   // (y1, xb..xb+1)
        }
    };
    auto comp = [&](const f2u (&t)[4], const f2u (&bo)[4], int c) {
        f4 v;
        #pragma unroll
        for (int i = 0; i < 4; ++i)
            v[i] = wtx[i] * t[i].x + wty[i] * t[i].y
                 + wbx[i] * bo[i].x + wby[i] * bo[i].y;
        __builtin_nontemporal_store(v, (f4*)(outb + (size_t)c * HWSZ + hw));
    };

    f2u At[4], Ab[4], Bt[4], Bb[4], Ct[4], Cb[4], Dt[4], Db[4];

    loadc(At, Ab, 0);
    loadc(Bt, Bb, 1);
    loadc(Ct, Cb, 2);
    loadc(Dt, Db, 3);

    comp(At, Ab, 0);   loadc(At, Ab, 4);
    comp(Bt, Bb, 1);   loadc(Bt, Bb, 5);
    comp(Ct, Cb, 2);   loadc(Ct, Cb, 6);
    comp(Dt, Db, 3);   loadc(Dt, Db, 7);

    comp(At, Ab, 4);   loadc(At, Ab, 8);
    comp(Bt, Bb, 5);   loadc(Bt, Bb, 9);
    comp(Ct, Cb, 6);   loadc(Ct, Cb, 10);
    comp(Dt, Db, 7);   loadc(Dt, Db, 11);

    comp(At, Ab, 8);   loadc(At, Ab, 12);
    comp(Bt, Bb, 9);   loadc(Bt, Bb, 13);
    comp(Ct, Cb, 10);  loadc(Ct, Cb, 14);
    comp(Dt, Db, 11);  loadc(Dt, Db, 15);

    comp(At, Ab, 12);
    comp(Bt, Bb, 13);
    comp(Ct, Cb, 14);
    comp(Dt, Db, 15);
}

extern "C" void kernel_launch(void* const* d_in, const int* in_sizes, int n_in,
                              void* d_out, int out_size, void* d_ws, size_t ws_size,
                              hipStream_t stream)
{
    const float* img = (const float*)d_in[0];
    const float* flo = (const float*)d_in[1];
    float*       out = (float*)d_out;

    warp_bilinear_kernel<<<NBLOCKS, 256, 0, stream>>>(img, flo, out);
}